// Round 6
// baseline (267.011 us; speedup 1.0000x reference)
//
#include <hip/hip_runtime.h>

// GraphSAGE 2-layer. N=50000, E=800000, D_IN=128, D_H=256, D_OUT=128.
//
// R12: gemm_fused de-stall. R11 counters: MfmaUtil 10.7%, occupancy 25%,
// 1.6M LDS bank-conflict cycles, 67.6KB LDS -> stall-dominated (pipe floor
// ~6us, measured 42.8us). Changes:
//  1. As/Hs aliased into ONE 33.8KB buffer (read A -> barrier -> write H in
//     place -> barrier -> read H). LDS no longer caps residency.
//  2. Swapped MFMA operands (mfma(wr,af)): D-rows=j, D-cols=node -> lane owns
//     4 consecutive j -> epilogue A = packed uint2 LDS writes (kills the u16
//     scatter conflicts), epilogue B = packed uint2 tb / float4 out stores,
//     float4 bias loads.
//  3. wr[2][4] (32 VGPR) k-half-resident W with mid-phase reload
//     (sched_barrier(0) pins reload placement) -> lower unified reg footprint
//     -> more blocks/CU for latency hiding.
//
// Pipeline:
//   prep | hist | scan_blocks/scan_add | fill  (CSR build)
//   gather1: A1 cols 0..127 = mean_{s in adj(n)} bf16(x[s])
//   gemm_fused: H=relu(A1@Wc1.T+b1) in LDS; tb=H@W2l.T (bf16);
//               out=H@W2r.T+b2l (fp32)
//   gather2: out[n] += mean_{s in adj(n)} tb[s]
//
// Layer-2 trick: mean(h[src])@W2l.T == mean((h@W2l.T)[src]).

typedef __attribute__((ext_vector_type(8))) short bf16x8;
typedef __attribute__((ext_vector_type(4))) float floatx4;

__device__ inline unsigned short f2b(float f) {
  unsigned int x = __float_as_uint(f);
  unsigned int r = (x + 0x7fffu + ((x >> 16) & 1u)) >> 16;
  return (unsigned short)r;
}
__device__ inline float blo(unsigned int u) { return __uint_as_float(u << 16); }
__device__ inline float bhi(unsigned int u) { return __uint_as_float(u & 0xffff0000u); }

// Fused prep: weight pack, x->bf16 convert, cnt zero, off[N]=E.
__global__ void prep_kernel(const float* __restrict__ x,
                            const float* __restrict__ W1l, const float* __restrict__ W1r,
                            const float* __restrict__ W2l, const float* __restrict__ W2r,
                            unsigned short* __restrict__ Wc1, unsigned short* __restrict__ Wc2,
                            unsigned short* __restrict__ A1,
                            int* __restrict__ cnt, int* __restrict__ off, int N, int E) {
  int i = blockIdx.x * blockDim.x + threadIdx.x;
  if (i < 65536) {
    int j = i >> 8, k = i & 255;
    float v1 = (k < 128) ? W1l[j * 128 + k] : W1r[j * 128 + (k - 128)];
    Wc1[i] = f2b(v1);
    float v2 = (j < 128) ? W2l[j * 256 + k] : W2r[(j - 128) * 256 + k];
    Wc2[i] = f2b(v2);
  }
  if (i < N) cnt[i] = 0;
  if (i == 0) off[N] = E;
  if (i < N * 32) {
    int n = i >> 5, c = (i & 31) * 4;
    float4 v = *(const float4*)(x + (size_t)n * 128 + c);
    uint2 p;
    p.x = (unsigned int)f2b(v.x) | ((unsigned int)f2b(v.y) << 16);
    p.y = (unsigned int)f2b(v.z) | ((unsigned int)f2b(v.w) << 16);
    *(uint2*)(A1 + (size_t)n * 256 + 128 + c) = p;
  }
}

// Histogram + per-edge rank capture (4 edges/thread, vectorized loads).
__global__ void hist_kernel(const int* __restrict__ dst, int* __restrict__ cnt,
                            int* __restrict__ rank, int E) {
  int i = blockIdx.x * blockDim.x + threadIdx.x;
  int e = i * 4;
  if (e + 3 < E) {
    int4 d = *(const int4*)(dst + e);
    int4 r;
    r.x = atomicAdd(&cnt[d.x], 1);
    r.y = atomicAdd(&cnt[d.y], 1);
    r.z = atomicAdd(&cnt[d.z], 1);
    r.w = atomicAdd(&cnt[d.w], 1);
    *(int4*)(rank + e) = r;
  } else {
    for (; e < E; e++) rank[e] = atomicAdd(&cnt[dst[e]], 1);
  }
}

// Per-1024-block exclusive scan; block total -> bsum[b].
__global__ __launch_bounds__(1024) void scan_blocks_kernel(const int* __restrict__ cnt,
                                                           int* __restrict__ off,
                                                           int* __restrict__ bsum, int N) {
  __shared__ int wsum[16];
  __shared__ int wincl[16];
  const int tid = threadIdx.x;
  const int lane = tid & 63;
  const int wv = tid >> 6;
  const int i = blockIdx.x * 1024 + tid;
  const int v = (i < N) ? cnt[i] : 0;
  int s = v;
#pragma unroll
  for (int o = 1; o < 64; o <<= 1) {
    int t = __shfl_up(s, o, 64);
    if (lane >= o) s += t;
  }
  if (lane == 63) wsum[wv] = s;
  __syncthreads();
  if (tid < 16) {
    int ws = wsum[tid];
#pragma unroll
    for (int o = 1; o < 16; o <<= 1) {
      int t = __shfl_up(ws, o, 16);
      if ((tid & 15) >= o) ws += t;
    }
    wincl[tid] = ws;
  }
  __syncthreads();
  const int wo = wv ? wincl[wv - 1] : 0;
  if (i < N) off[i] = wo + s - v;
  if (tid == 1023) bsum[blockIdx.x] = wo + s;
}

// Add block offsets (block-sum scan inlined: <=64 sums, wave 0).
__global__ __launch_bounds__(1024) void scan_add_kernel(int* __restrict__ off,
                                                        const int* __restrict__ bsum, int N, int SB) {
  __shared__ int bofs[64];
  const int tid = threadIdx.x;
  if (tid < 64) {
    int v = (tid < SB) ? bsum[tid] : 0;
    int s = v;
#pragma unroll
    for (int o = 1; o < 64; o <<= 1) {
      int t = __shfl_up(s, o, 64);
      if (tid >= o) s += t;
    }
    bofs[tid] = s - v;
  }
  __syncthreads();
  int i = blockIdx.x * 1024 + tid;
  if (i < N) off[i] = off[i] + bofs[blockIdx.x];
}

// Atomic-free fill: plain scattered stores, 4 edges/thread.
__global__ void fill_kernel(const int* __restrict__ src, const int* __restrict__ dst,
                            const int* __restrict__ rank, const int* __restrict__ off,
                            int* __restrict__ csr, int E) {
  int i = blockIdx.x * blockDim.x + threadIdx.x;
  int e = i * 4;
  if (e + 3 < E) {
    int4 d = *(const int4*)(dst + e);
    int4 r = *(const int4*)(rank + e);
    int4 s = *(const int4*)(src + e);
    csr[off[d.x] + r.x] = s.x;
    csr[off[d.y] + r.y] = s.y;
    csr[off[d.z] + r.z] = s.z;
    csr[off[d.w] + r.w] = s.w;
  } else {
    for (; e < E; e++) csr[off[dst[e]] + rank[e]] = src[e];
  }
}

// Gather-mean, one wave per node, 64 lanes per edge-row. Lane l owns columns
// 2l,2l+1 (one dword of the 256B row): no cross-lane reduction; coalesced
// 1-dword/lane loads. 8-edge unroll -> 8 row-loads outstanding; 2-edge
// mid-tail. Edge ids via lane-parallel csr read + __shfl broadcast.
__global__ void gather1_kernel(const unsigned short* __restrict__ feat,
                               const int* __restrict__ csr, const int* __restrict__ off,
                               unsigned short* __restrict__ ob, int N) {
  int wid = (blockIdx.x * blockDim.x + threadIdx.x) >> 6;
  if (wid >= N) return;
  const int lane = threadIdx.x & 63;
  const int s0 = off[wid], s1 = off[wid + 1];
  float a0 = 0.f, a1 = 0.f;
  for (int base = s0; base < s1; base += 64) {
    const int cnt = min(64, s1 - base);
    int my = (lane < cnt) ? csr[base + lane] : 0;
    int k = 0;
    for (; k + 8 <= cnt; k += 8) {
      int i0 = __shfl(my, k);
      int i1 = __shfl(my, k + 1);
      int i2 = __shfl(my, k + 2);
      int i3 = __shfl(my, k + 3);
      int i4 = __shfl(my, k + 4);
      int i5 = __shfl(my, k + 5);
      int i6 = __shfl(my, k + 6);
      int i7 = __shfl(my, k + 7);
      unsigned u0 = ((const unsigned*)(feat + (size_t)i0 * 256))[lane];
      unsigned u1 = ((const unsigned*)(feat + (size_t)i1 * 256))[lane];
      unsigned u2 = ((const unsigned*)(feat + (size_t)i2 * 256))[lane];
      unsigned u3 = ((const unsigned*)(feat + (size_t)i3 * 256))[lane];
      unsigned u4 = ((const unsigned*)(feat + (size_t)i4 * 256))[lane];
      unsigned u5 = ((const unsigned*)(feat + (size_t)i5 * 256))[lane];
      unsigned u6 = ((const unsigned*)(feat + (size_t)i6 * 256))[lane];
      unsigned u7 = ((const unsigned*)(feat + (size_t)i7 * 256))[lane];
      a0 += blo(u0); a1 += bhi(u0);
      a0 += blo(u1); a1 += bhi(u1);
      a0 += blo(u2); a1 += bhi(u2);
      a0 += blo(u3); a1 += bhi(u3);
      a0 += blo(u4); a1 += bhi(u4);
      a0 += blo(u5); a1 += bhi(u5);
      a0 += blo(u6); a1 += bhi(u6);
      a0 += blo(u7); a1 += bhi(u7);
    }
    for (; k + 2 <= cnt; k += 2) {
      int i0 = __shfl(my, k);
      int i1 = __shfl(my, k + 1);
      unsigned u0 = ((const unsigned*)(feat + (size_t)i0 * 256))[lane];
      unsigned u1 = ((const unsigned*)(feat + (size_t)i1 * 256))[lane];
      a0 += blo(u0); a1 += bhi(u0);
      a0 += blo(u1); a1 += bhi(u1);
    }
    if (k < cnt) {
      int i0 = __shfl(my, k);
      unsigned u0 = ((const unsigned*)(feat + (size_t)i0 * 256))[lane];
      a0 += blo(u0); a1 += bhi(u0);
    }
  }
  const float inv = 1.0f / fmaxf((float)(s1 - s0), 1.0f);
  unsigned p = (unsigned)f2b(a0 * inv) | ((unsigned)f2b(a1 * inv) << 16);
  ((unsigned*)(ob + (size_t)wid * 256))[lane] = p;
}

// Same structure; feat (tb) stride 128 ushorts; accumulate into fp32 out.
// out row prefetched BEFORE the loop (overlaps gather latency).
__global__ void gather2_kernel(const unsigned short* __restrict__ t,
                               const int* __restrict__ csr, const int* __restrict__ off,
                               float* __restrict__ out, int N) {
  int wid = (blockIdx.x * blockDim.x + threadIdx.x) >> 6;
  if (wid >= N) return;
  const int lane = threadIdx.x & 63;
  const int s0 = off[wid], s1 = off[wid + 1];
  float2* op = (float2*)(out + (size_t)wid * 128) + lane;
  float2 r = *op;  // prefetch RMW operand early
  float a0 = 0.f, a1 = 0.f;
  for (int base = s0; base < s1; base += 64) {
    const int cnt = min(64, s1 - base);
    int my = (lane < cnt) ? csr[base + lane] : 0;
    int k = 0;
    for (; k + 8 <= cnt; k += 8) {
      int i0 = __shfl(my, k);
      int i1 = __shfl(my, k + 1);
      int i2 = __shfl(my, k + 2);
      int i3 = __shfl(my, k + 3);
      int i4 = __shfl(my, k + 4);
      int i5 = __shfl(my, k + 5);
      int i6 = __shfl(my, k + 6);
      int i7 = __shfl(my, k + 7);
      unsigned u0 = ((const unsigned*)(t + (size_t)i0 * 128))[lane];
      unsigned u1 = ((const unsigned*)(t + (size_t)i1 * 128))[lane];
      unsigned u2 = ((const unsigned*)(t + (size_t)i2 * 128))[lane];
      unsigned u3 = ((const unsigned*)(t + (size_t)i3 * 128))[lane];
      unsigned u4 = ((const unsigned*)(t + (size_t)i4 * 128))[lane];
      unsigned u5 = ((const unsigned*)(t + (size_t)i5 * 128))[lane];
      unsigned u6 = ((const unsigned*)(t + (size_t)i6 * 128))[lane];
      unsigned u7 = ((const unsigned*)(t + (size_t)i7 * 128))[lane];
      a0 += blo(u0); a1 += bhi(u0);
      a0 += blo(u1); a1 += bhi(u1);
      a0 += blo(u2); a1 += bhi(u2);
      a0 += blo(u3); a1 += bhi(u3);
      a0 += blo(u4); a1 += bhi(u4);
      a0 += blo(u5); a1 += bhi(u5);
      a0 += blo(u6); a1 += bhi(u6);
      a0 += blo(u7); a1 += bhi(u7);
    }
    for (; k + 2 <= cnt; k += 2) {
      int i0 = __shfl(my, k);
      int i1 = __shfl(my, k + 1);
      unsigned u0 = ((const unsigned*)(t + (size_t)i0 * 128))[lane];
      unsigned u1 = ((const unsigned*)(t + (size_t)i1 * 128))[lane];
      a0 += blo(u0); a1 += bhi(u0);
      a0 += blo(u1); a1 += bhi(u1);
    }
    if (k < cnt) {
      int i0 = __shfl(my, k);
      unsigned u0 = ((const unsigned*)(t + (size_t)i0 * 128))[lane];
      a0 += blo(u0); a1 += bhi(u0);
    }
  }
  const float inv = 1.0f / fmaxf((float)(s1 - s0), 1.0f);
  r.x += a0 * inv;
  r.y += a1 * inv;
  *op = r;
}

// Fused 2-layer bf16 MFMA GEMM. 512 thr = 8 waves; wave w: j-cols
// [w*32,w*32+32), m-rows 0..63. Swapped operands: acc=mfma(wr,af) -> D rows=j
// (quad*4+r), D cols=node (l15) -> packed epilogues. wr[2][4] holds one
// k-half (32 VGPR), reloaded mid-phase. As/Hs aliased (33.8KB), 3 barriers.
__global__ __launch_bounds__(512, 4)
void gemm_fused(const unsigned short* __restrict__ A, const unsigned short* __restrict__ Wc1,
                const unsigned short* __restrict__ Wc2,
                const float* __restrict__ b1, const float* __restrict__ b2,
                unsigned short* __restrict__ tb, float* __restrict__ out, int M) {
  constexpr int LDA = 264;  // 132 dw == 4 banks mod 32
  __shared__ __align__(16) unsigned short AH[64 * LDA];  // As, then Hs (aliased)
  const int t = threadIdx.x;
  const int lane = t & 63;
  const int wave = t >> 6;
  const int wn = wave * 32;
  const int l15 = lane & 15;
  const int quad = lane >> 4;
  const int m_blk = blockIdx.x * 64;

  // Stage A tile (64 rows x 256 k = 32 KB): issue global loads first.
  uint4 sv[4];
  int srow[4], scol[4];
#pragma unroll
  for (int i = 0; i < 4; i++) {
    int idx = t + 512 * i;
    srow[i] = idx >> 5;
    scol[i] = (idx & 31) * 8;
    int ar = m_blk + srow[i];
    if (ar >= M) ar = M - 1;
    sv[i] = *(const uint4*)(A + (size_t)ar * 256 + scol[i]);
  }

  // W1 fragments, k-half 0 (k 0..127): wr[nt][c], j = wn+nt*16+l15.
  bf16x8 wr[2][4];
#pragma unroll
  for (int nt = 0; nt < 2; nt++) {
    const unsigned short* wp = Wc1 + (size_t)(wn + nt * 16 + l15) * 256 + quad * 8;
#pragma unroll
    for (int c = 0; c < 4; c++) wr[nt][c] = *(const bf16x8*)(wp + c * 32);
  }
  // Bias (4 consecutive j per lane).
  float4 bq[2];
#pragma unroll
  for (int nt = 0; nt < 2; nt++)
    bq[nt] = *(const float4*)(b1 + wn + nt * 16 + quad * 4);

#pragma unroll
  for (int i = 0; i < 4; i++)
    *(uint4*)(AH + srow[i] * LDA + scol[i]) = sv[i];
  __syncthreads();

  floatx4 acc[4][2] = {};

  // ---- Phase A: acc[j][node] = Wc1 @ A.T ----
#pragma unroll
  for (int c = 0; c < 4; c++) {
    bf16x8 af[4];
#pragma unroll
    for (int mt = 0; mt < 4; mt++)
      af[mt] = *(const bf16x8*)(AH + (mt * 16 + l15) * LDA + c * 32 + quad * 8);
#pragma unroll
    for (int mt = 0; mt < 4; mt++) {
      acc[mt][0] = __builtin_amdgcn_mfma_f32_16x16x32_bf16(wr[0][c], af[mt], acc[mt][0], 0, 0, 0);
      acc[mt][1] = __builtin_amdgcn_mfma_f32_16x16x32_bf16(wr[1][c], af[mt], acc[mt][1], 0, 0, 0);
    }
  }
  __builtin_amdgcn_sched_barrier(0);
  // Reload wr with W1 k-half 1 (k 128..255).
#pragma unroll
  for (int nt = 0; nt < 2; nt++) {
    const unsigned short* wp = Wc1 + (size_t)(wn + nt * 16 + l15) * 256 + 128 + quad * 8;
#pragma unroll
    for (int c = 0; c < 4; c++) wr[nt][c] = *(const bf16x8*)(wp + c * 32);
  }
#pragma unroll
  for (int c = 0; c < 4; c++) {
    bf16x8 af[4];
#pragma unroll
    for (int mt = 0; mt < 4; mt++)
      af[mt] = *(const bf16x8*)(AH + (mt * 16 + l15) * LDA + 128 + c * 32 + quad * 8);
#pragma unroll
    for (int mt = 0; mt < 4; mt++) {
      acc[mt][0] = __builtin_amdgcn_mfma_f32_16x16x32_bf16(wr[0][c], af[mt], acc[mt][0], 0, 0, 0);
      acc[mt][1] = __builtin_amdgcn_mfma_f32_16x16x32_bf16(wr[1][c], af[mt], acc[mt][1], 0, 0, 0);
    }
  }
  __builtin_amdgcn_sched_barrier(0);
  // Load W2 k-half 0 early (overlaps epilogue A + barriers).
#pragma unroll
  for (int nt = 0; nt < 2; nt++) {
    const unsigned short* wp = Wc2 + (size_t)(wn + nt * 16 + l15) * 256 + quad * 8;
#pragma unroll
    for (int c = 0; c < 4; c++) wr[nt][c] = *(const bf16x8*)(wp + c * 32);
  }
  __syncthreads();  // all As reads done -> safe to overwrite with Hs

  // Epilogue A: H = relu(acc + b1), packed uint2 into AH (node-row, j-col).
#pragma unroll
  for (int mt = 0; mt < 4; mt++) {
#pragma unroll
    for (int nt = 0; nt < 2; nt++) {
      const int node = mt * 16 + l15;
      const int j0 = wn + nt * 16 + quad * 4;
      uint2 p;
      p.x = (unsigned)f2b(fmaxf(acc[mt][nt][0] + bq[nt].x, 0.f)) |
            ((unsigned)f2b(fmaxf(acc[mt][nt][1] + bq[nt].y, 0.f)) << 16);
      p.y = (unsigned)f2b(fmaxf(acc[mt][nt][2] + bq[nt].z, 0.f)) |
            ((unsigned)f2b(fmaxf(acc[mt][nt][3] + bq[nt].w, 0.f)) << 16);
      *(uint2*)(AH + node * LDA + j0) = p;
    }
  }
  // b2 bias for the out-half waves (j>=128).
  if (wn >= 128) {
#pragma unroll
    for (int nt = 0; nt < 2; nt++)
      bq[nt] = *(const float4*)(b2 + wn - 128 + nt * 16 + quad * 4);
  }
  __syncthreads();  // Hs complete

  // ---- Phase B: acc[j][node] = Wc2 @ H.T ----
#pragma unroll
  for (int mt = 0; mt < 4; mt++) {
    acc[mt][0] = (floatx4){0.f, 0.f, 0.f, 0.f};
    acc[mt][1] = (floatx4){0.f, 0.f, 0.f, 0.f};
  }
#pragma unroll
  for (int c = 0; c < 4; c++) {
    bf16x8 hf[4];
#pragma unroll
    for (int mt = 0; mt < 4; mt++)
      hf[mt] = *(const bf16x8*)(AH + (mt * 16 + l15) * LDA + c * 32 + quad * 8);
#pragma unroll
    for (int mt = 0; mt < 4; mt++) {
      acc[mt][0] = __builtin_amdgcn_mfma_f32_16x16x32_bf16(wr[0][c], hf[mt], acc[mt][0], 0, 0, 0);
      acc[mt][1] = __builtin_amdgcn_mfma_f32_16x16x32_bf16(wr[1][c], hf[mt], acc[mt][1], 0, 0, 0);
    }
  }
  __builtin_amdgcn_sched_barrier(0);
  // Reload wr with W2 k-half 1.
#pragma unroll
  for (int nt = 0; nt < 2; nt++) {
    const unsigned short* wp = Wc2 + (size_t)(wn + nt * 16 + l15) * 256 + 128 + quad * 8;
#pragma unroll
    for (int c = 0; c < 4; c++) wr[nt][c] = *(const bf16x8*)(wp + c * 32);
  }
#pragma unroll
  for (int c = 0; c < 4; c++) {
    bf16x8 hf[4];
#pragma unroll
    for (int mt = 0; mt < 4; mt++)
      hf[mt] = *(const bf16x8*)(AH + (mt * 16 + l15) * LDA + 128 + c * 32 + quad * 8);
#pragma unroll
    for (int mt = 0; mt < 4; mt++) {
      acc[mt][0] = __builtin_amdgcn_mfma_f32_16x16x32_bf16(wr[0][c], hf[mt], acc[mt][0], 0, 0, 0);
      acc[mt][1] = __builtin_amdgcn_mfma_f32_16x16x32_bf16(wr[1][c], hf[mt], acc[mt][1], 0, 0, 0);
    }
  }

  // Epilogue B: waves 0-3 (j<128): packed uint2 tb (=h@W2l.T, bf16);
  //             waves 4-7: packed float4 out (=h@W2r.T + b2l, fp32).
#pragma unroll
  for (int mt = 0; mt < 4; mt++) {
    const int node = m_blk + mt * 16 + l15;
    if (node >= M) continue;
#pragma unroll
    for (int nt = 0; nt < 2; nt++) {
      const int j0 = wn + nt * 16 + quad * 4;
      if (wn < 128) {
        uint2 p;
        p.x = (unsigned)f2b(acc[mt][nt][0]) | ((unsigned)f2b(acc[mt][nt][1]) << 16);
        p.y = (unsigned)f2b(acc[mt][nt][2]) | ((unsigned)f2b(acc[mt][nt][3]) << 16);
        *(uint2*)(tb + (size_t)node * 128 + j0) = p;
      } else {
        float4 o;
        o.x = acc[mt][nt][0] + bq[nt].x;
        o.y = acc[mt][nt][1] + bq[nt].y;
        o.z = acc[mt][nt][2] + bq[nt].z;
        o.w = acc[mt][nt][3] + bq[nt].w;
        *(float4*)(out + (size_t)node * 128 + (j0 - 128)) = o;
      }
    }
  }
}

extern "C" void kernel_launch(void* const* d_in, const int* in_sizes, int n_in,
                              void* d_out, int out_size, void* d_ws, size_t ws_size,
                              hipStream_t stream) {
  const float* x   = (const float*)d_in[0];
  const int*  eidx = (const int*)d_in[1];
  const float* W1l = (const float*)d_in[2];
  const float* b1l = (const float*)d_in[3];
  const float* W1r = (const float*)d_in[4];
  const float* W2l = (const float*)d_in[5];
  const float* b2l = (const float*)d_in[6];
  const float* W2r = (const float*)d_in[7];
  float* out = (float*)d_out;

  const int N = in_sizes[0] / 128;
  const int E = in_sizes[1] / 2;
  const int* src = eidx;
  const int* dst = eidx + E;

  int* cnt  = (int*)d_ws;          // [N]
  int* off  = cnt + N;             // [N+1]
  int* bsum = off + N + 1;         // [64]
  int* rank = bsum + 64;           // [E]
  int* csr  = rank + E;            // [E]
  size_t ioff = ((size_t)(N + N + 1 + 64 + 2 * E) * 4 + 15) & ~(size_t)15;
  unsigned short* A1  = (unsigned short*)((char*)d_ws + ioff);  // [N][256]
  unsigned short* tb  = A1 + (size_t)N * 256;                   // [N][128]
  unsigned short* Wc1 = tb + (size_t)N * 128;                   // [256][256]
  unsigned short* Wc2 = Wc1 + 65536;                            // [256][256]

  const int SB = (N + 1023) / 1024;  // 49

  prep_kernel<<<(N * 32 + 255) / 256, 256, 0, stream>>>(x, W1l, W1r, W2l, W2r,
                                                        Wc1, Wc2, A1, cnt, off, N, E);
  hist_kernel<<<(E / 4 + 255) / 256, 256, 0, stream>>>(dst, cnt, rank, E);
  scan_blocks_kernel<<<SB, 1024, 0, stream>>>(cnt, off, bsum, N);
  scan_add_kernel<<<SB, 1024, 0, stream>>>(off, bsum, N, SB);
  fill_kernel<<<(E / 4 + 255) / 256, 256, 0, stream>>>(src, dst, rank, off, csr, E);

  const int gblocks = (N + 3) / 4;  // 1 wave (64 lanes) per node
  gather1_kernel<<<gblocks, 256, 0, stream>>>(A1 + 128, csr, off, A1, N);

  gemm_fused<<<(N + 63) / 64, 512, 0, stream>>>(A1, Wc1, Wc2, b1l, b2l, tb, out, N);

  gather2_kernel<<<gblocks, 256, 0, stream>>>(tb, csr, off, out, N);
}